// Round 1
// baseline (1251.944 us; speedup 1.0000x reference)
//
#include <hip/hip_runtime.h>
#include <cmath>

// Problem constants (match reference)
#define NN 20000     // N_NODES
#define NP 100000    // N_PATHS
#define D  128       // D_IN == H
#define G4 512       // 4*H gate width
#define NG 128       // N_GRAPHS
#define NC 10        // N_CLASSES
#define CHUNK 20000  // path_3 processing chunk (NP % CHUNK == 0 handled generically)

__device__ __forceinline__ float sigf(float x) { return 1.0f / (1.0f + expf(-x)); }

// ---------------------------------------------------------------------------
// GEMM: C[M,N] = A[M,128] @ W[N,128]^T (+bias[N]) (optional relu). K=128 fixed.
// 64x64 tile, 256 threads, 4x4 per thread. LDS pad 129 -> bank = (row+k)%32,
// <=2-way conflicts on compute reads (free per m136).
// ---------------------------------------------------------------------------
__global__ __launch_bounds__(256) void gemm_k128(
    const float* __restrict__ A, const float* __restrict__ W,
    const float* __restrict__ bias, float* __restrict__ C,
    int M, int N, int relu)
{
  __shared__ float As[64][129];
  __shared__ float Ws[64][129];
  const int tid = threadIdx.x;
  const int bm = blockIdx.x * 64;
  const int bn = blockIdx.y * 64;

#pragma unroll
  for (int pass = 0; pass < 8; ++pass) {
    int r  = pass * 8 + (tid >> 5);
    int c4 = (tid & 31) * 4;
    float4 va = make_float4(0.f, 0.f, 0.f, 0.f);
    int ga = bm + r;
    if (ga < M) va = *(const float4*)(A + (size_t)ga * 128 + c4);
    As[r][c4 + 0] = va.x; As[r][c4 + 1] = va.y; As[r][c4 + 2] = va.z; As[r][c4 + 3] = va.w;
    float4 vw = make_float4(0.f, 0.f, 0.f, 0.f);
    int gw = bn + r;
    if (gw < N) vw = *(const float4*)(W + (size_t)gw * 128 + c4);
    Ws[r][c4 + 0] = vw.x; Ws[r][c4 + 1] = vw.y; Ws[r][c4 + 2] = vw.z; Ws[r][c4 + 3] = vw.w;
  }
  __syncthreads();

  const int tm = (tid >> 4) * 4;  // 0..60
  const int tn = (tid & 15) * 4;  // 0..60
  float acc[4][4] = {};

#pragma unroll 8
  for (int k = 0; k < 128; ++k) {
    float a0 = As[tm + 0][k], a1 = As[tm + 1][k], a2 = As[tm + 2][k], a3 = As[tm + 3][k];
    float w0 = Ws[tn + 0][k], w1 = Ws[tn + 1][k], w2 = Ws[tn + 2][k], w3 = Ws[tn + 3][k];
    acc[0][0] += a0 * w0; acc[0][1] += a0 * w1; acc[0][2] += a0 * w2; acc[0][3] += a0 * w3;
    acc[1][0] += a1 * w0; acc[1][1] += a1 * w1; acc[1][2] += a1 * w2; acc[1][3] += a1 * w3;
    acc[2][0] += a2 * w0; acc[2][1] += a2 * w1; acc[2][2] += a2 * w2; acc[2][3] += a2 * w3;
    acc[3][0] += a3 * w0; acc[3][1] += a3 * w1; acc[3][2] += a3 * w2; acc[3][3] += a3 * w3;
  }

#pragma unroll
  for (int i = 0; i < 4; ++i) {
    int r = bm + tm + i;
    if (r >= M) continue;
#pragma unroll
    for (int j = 0; j < 4; ++j) {
      int cn = bn + tn + j;
      if (cn >= N) continue;
      float v = acc[i][j] + (bias ? bias[cn] : 0.f);
      if (relu) v = fmaxf(v, 0.f);
      C[(size_t)r * N + cn] = v;
    }
  }
}

// ---------------------------------------------------------------------------
// BatchNorm: column sum/sumsq over [M,128], then apply + relu.
// ---------------------------------------------------------------------------
__global__ void zero_kernel(float* p, int n) {
  for (int i = blockIdx.x * blockDim.x + threadIdx.x; i < n; i += gridDim.x * blockDim.x)
    p[i] = 0.f;
}

__global__ void addvec_kernel(const float* a, const float* b, float* o, int n) {
  int i = blockIdx.x * blockDim.x + threadIdx.x;
  if (i < n) o[i] = a[i] + b[i];
}

__global__ __launch_bounds__(256) void bn_stats(const float* __restrict__ u,
                                                float* __restrict__ stats,
                                                int M, int rowsPerBlock) {
  __shared__ float sh[512];
  const int j = threadIdx.x & 127;
  const int half = threadIdx.x >> 7;  // 0/1
  int r0 = blockIdx.x * rowsPerBlock;
  int r1 = min(M, r0 + rowsPerBlock);
  float s = 0.f, q = 0.f;
  for (int r = r0 + half; r < r1; r += 2) {
    float v = u[(size_t)r * 128 + j];
    s += v; q += v * v;
  }
  sh[threadIdx.x] = s;
  sh[256 + threadIdx.x] = q;
  __syncthreads();
  if (threadIdx.x < 128) {
    atomicAdd(&stats[j], sh[j] + sh[j + 128]);
    atomicAdd(&stats[128 + j], sh[256 + j] + sh[256 + j + 128]);
  }
}

__global__ void bn_apply_relu(const float* __restrict__ u, const float* __restrict__ stats,
                              const float* __restrict__ g, const float* __restrict__ b,
                              float* __restrict__ out, int n, float invM) {
  int idx = blockIdx.x * blockDim.x + threadIdx.x;
  if (idx >= n) return;
  int j = idx & 127;
  float m = stats[j] * invM;
  float var = stats[128 + j] * invM - m * m;
  float y = g[j] * (u[idx] - m) * rsqrtf(var + 1e-5f) + b[j];
  out[idx] = fmaxf(y, 0.f);
}

// ---------------------------------------------------------------------------
// LSTM pieces. Gate order (torch): i, f, g, o at offsets 0,128,256,384 in G4.
// Z already contains x@w_ih.T + b_ih + b_hh.
// ---------------------------------------------------------------------------
__global__ void lstm_step0(const float* __restrict__ Z, float* __restrict__ H1,
                           float* __restrict__ C1, int n) {
  int idx = blockIdx.x * blockDim.x + threadIdx.x;
  if (idx >= n) return;
  int v = idx >> 7, j = idx & 127;
  const float* z = Z + (size_t)v * G4;
  float gi = z[j], gg = z[256 + j], go = z[384 + j];
  float c = sigf(gi) * tanhf(gg);       // f-gate * c0 = 0
  float h = sigf(go) * tanhf(c);
  C1[idx] = c;
  H1[idx] = h;
}

// T=2 final step: gates = Z[b] + R1[a]; c2 = sig(f)*C1[a] + sig(i)*tanh(g);
// hf = sig(o)*tanh(c2); scatter-add into agg[b].
__global__ void lstm_final2(const int* __restrict__ path, const float* __restrict__ Z,
                            const float* __restrict__ R1, const float* __restrict__ C1,
                            float* __restrict__ agg, int n) {
  int idx = blockIdx.x * blockDim.x + threadIdx.x;
  if (idx >= n) return;
  int p = idx >> 7, j = idx & 127;
  int a = path[p * 2 + 0], b = path[p * 2 + 1];
  const float* z = Z + (size_t)b * G4;
  const float* r = R1 + (size_t)a * G4;
  float gi = z[j] + r[j];
  float gf = z[128 + j] + r[128 + j];
  float gg = z[256 + j] + r[256 + j];
  float go = z[384 + j] + r[384 + j];
  float c = sigf(gf) * C1[(size_t)a * 128 + j] + sigf(gi) * tanhf(gg);
  float hf = sigf(go) * tanhf(c);
  atomicAdd(&agg[(size_t)b * 128 + j], hf);
}

// T=3 middle step (chunked): gates = Z[b] + R1[a]; store h2,c2 per path-local.
__global__ void lstm_step1(const int* __restrict__ path, const float* __restrict__ Z,
                           const float* __restrict__ R1, const float* __restrict__ C1,
                           float* __restrict__ h2, float* __restrict__ c2, int n) {
  int idx = blockIdx.x * blockDim.x + threadIdx.x;
  if (idx >= n) return;
  int p = idx >> 7, j = idx & 127;
  int a = path[p * 3 + 0], b = path[p * 3 + 1];
  const float* z = Z + (size_t)b * G4;
  const float* r = R1 + (size_t)a * G4;
  float gi = z[j] + r[j];
  float gf = z[128 + j] + r[128 + j];
  float gg = z[256 + j] + r[256 + j];
  float go = z[384 + j] + r[384 + j];
  float c = sigf(gf) * C1[(size_t)a * 128 + j] + sigf(gi) * tanhf(gg);
  float h = sigf(go) * tanhf(c);
  c2[idx] = c;
  h2[idx] = h;
}

// T=3 final step (chunked): gates = Z[c_node] + R2[p_local]; scatter into agg[c_node].
__global__ void lstm_final3(const int* __restrict__ path, const float* __restrict__ Z,
                            const float* __restrict__ R2, const float* __restrict__ c2,
                            float* __restrict__ agg, int n) {
  int idx = blockIdx.x * blockDim.x + threadIdx.x;
  if (idx >= n) return;
  int p = idx >> 7, j = idx & 127;
  int cnode = path[p * 3 + 2];
  const float* z = Z + (size_t)cnode * G4;
  const float* r = R2 + (size_t)p * G4;
  float gi = z[j] + r[j];
  float gf = z[128 + j] + r[128 + j];
  float gg = z[256 + j] + r[256 + j];
  float go = z[384 + j] + r[384 + j];
  float c = sigf(gf) * c2[idx] + sigf(gi) * tanhf(gg);
  float hf = sigf(go) * tanhf(c);
  atomicAdd(&agg[(size_t)cnode * 128 + j], hf);
}

// ---------------------------------------------------------------------------
__global__ void pool_kernel(const float* __restrict__ h, const int* __restrict__ batch,
                            float* __restrict__ pooled, int n) {
  int idx = blockIdx.x * blockDim.x + threadIdx.x;
  if (idx >= n) return;
  int v = idx >> 7, j = idx & 127;
  atomicAdd(&pooled[(size_t)batch[v] * 128 + j], h[idx]);
}

// ---------------------------------------------------------------------------
extern "C" void kernel_launch(void* const* d_in, const int* in_sizes, int n_in,
                              void* d_out, int out_size, void* d_ws, size_t ws_size,
                              hipStream_t stream) {
  const float* x      = (const float*)d_in[0];
  const int*   path2  = (const int*)d_in[1];
  const int*   path3  = (const int*)d_in[2];
  const int*   batch  = (const int*)d_in[3];
  const float* fe_w1  = (const float*)d_in[4];
  const float* fe_b1  = (const float*)d_in[5];
  const float* fe_g1  = (const float*)d_in[6];
  const float* fe_be1 = (const float*)d_in[7];
  const float* fe_w2  = (const float*)d_in[8];
  const float* fe_b2  = (const float*)d_in[9];
  const float* fe_g2  = (const float*)d_in[10];
  const float* fe_be2 = (const float*)d_in[11];
  const float* w_ih   = (const float*)d_in[12];
  const float* w_hh   = (const float*)d_in[13];
  const float* b_ih   = (const float*)d_in[14];
  const float* b_hh   = (const float*)d_in[15];
  const float* bn1_g  = (const float*)d_in[16];
  const float* bn1_b  = (const float*)d_in[17];
  const float* bn2_g  = (const float*)d_in[18];
  const float* bn2_b  = (const float*)d_in[19];
  const float* lin1_w = (const float*)d_in[20];
  const float* lin1_b = (const float*)d_in[21];
  const float* lin2_w = (const float*)d_in[22];
  const float* lin2_b = (const float*)d_in[23];
  float* out = (float*)d_out;

  // workspace carve-up (all sizes multiples of 128 floats -> alignment ok)
  float* w = (float*)d_ws;
  float* h    = w; w += (size_t)NN * D;
  float* agg  = w; w += (size_t)NN * D;
  float* Z    = w; w += (size_t)NN * G4;
  float* R1   = w; w += (size_t)NN * G4;
  float* H1   = w; w += (size_t)NN * D;
  float* C1   = w; w += (size_t)NN * D;
  float* h2c  = w; w += (size_t)CHUNK * D;
  float* c2c  = w; w += (size_t)CHUNK * D;
  float* R2c  = w; w += (size_t)CHUNK * G4;
  float* stats  = w; w += 256;
  float* pooled = w; w += (size_t)NG * D;
  float* out1   = w; w += (size_t)NG * D;
  float* bcomb  = w; w += G4;
  float* ency = Z;  // encoder temp reuses Z space (Z not live yet)

  auto gemm = [&](const float* A, const float* Wm, const float* bias, float* Cm,
                  int M, int N, bool relu) {
    dim3 g((M + 63) / 64, (N + 63) / 64);
    gemm_k128<<<g, 256, 0, stream>>>(A, Wm, bias, Cm, M, N, relu ? 1 : 0);
  };
  auto bn = [&](const float* u, const float* gamma, const float* beta, float* o, int M) {
    zero_kernel<<<1, 256, 0, stream>>>(stats, 256);
    const int blocks = 160;
    int rows = (M + blocks - 1) / blocks;
    bn_stats<<<blocks, 256, 0, stream>>>(u, stats, M, rows);
    int n = M * D;
    bn_apply_relu<<<(n + 255) / 256, 256, 0, stream>>>(u, stats, gamma, beta, o, n, 1.0f / M);
  };

  // combined LSTM input bias (b_ih + b_hh), folded into Z's GEMM epilogue
  addvec_kernel<<<2, 256, 0, stream>>>(b_ih, b_hh, bcomb, G4);

  // ---- feature encoder: Linear -> BN -> ReLU, twice ----
  gemm(x, fe_w1, fe_b1, ency, NN, D, false);
  bn(ency, fe_g1, fe_be1, h, NN);
  gemm(h, fe_w2, fe_b2, ency, NN, D, false);
  bn(ency, fe_g2, fe_be2, h, NN);

  // ---- PathConv layer 1 (T=2) ----
  // Per-node precompute: Z = h@w_ih.T + bias; (H1,C1) = step0(Z); R1 = H1@w_hh.T
  gemm(h, w_ih, bcomb, Z, NN, G4, false);
  lstm_step0<<<(NN * D + 255) / 256, 256, 0, stream>>>(Z, H1, C1, NN * D);
  gemm(H1, w_hh, nullptr, R1, NN, G4, false);
  hipMemcpyAsync(agg, h, (size_t)NN * D * sizeof(float), hipMemcpyDeviceToDevice, stream);
  lstm_final2<<<(NP * D + 255) / 256, 256, 0, stream>>>(path2, Z, R1, C1, agg, NP * D);
  bn(agg, bn1_g, bn1_b, h, NN);

  // ---- PathConv layer 2 (T=3) ----
  gemm(h, w_ih, bcomb, Z, NN, G4, false);
  lstm_step0<<<(NN * D + 255) / 256, 256, 0, stream>>>(Z, H1, C1, NN * D);
  gemm(H1, w_hh, nullptr, R1, NN, G4, false);
  hipMemcpyAsync(agg, h, (size_t)NN * D * sizeof(float), hipMemcpyDeviceToDevice, stream);
  for (int p0 = 0; p0 < NP; p0 += CHUNK) {
    int pc = NP - p0 < CHUNK ? NP - p0 : CHUNK;
    int n = pc * D;
    lstm_step1<<<(n + 255) / 256, 256, 0, stream>>>(path3 + (size_t)p0 * 3, Z, R1, C1,
                                                    h2c, c2c, n);
    gemm(h2c, w_hh, nullptr, R2c, pc, G4, false);   // the only per-path GEMM
    lstm_final3<<<(n + 255) / 256, 256, 0, stream>>>(path3 + (size_t)p0 * 3, Z, R2c, c2c,
                                                     agg, n);
  }
  bn(agg, bn2_g, bn2_b, h, NN);

  // ---- global add pool + MLP head ----
  zero_kernel<<<64, 256, 0, stream>>>(pooled, NG * D);
  pool_kernel<<<(NN * D + 255) / 256, 256, 0, stream>>>(h, batch, pooled, NN * D);
  gemm(pooled, lin1_w, lin1_b, out1, NG, D, true);
  gemm(out1, lin2_w, lin2_b, out, NG, NC, false);
}